// Round 16
// baseline (319.185 us; speedup 1.0000x reference)
//
#include <hip/hip_runtime.h>
#include <math.h>

typedef __attribute__((ext_vector_type(4))) float f32x4;
typedef __attribute__((ext_vector_type(8))) short bf16x8;
typedef __attribute__((ext_vector_type(4))) short s16x4;

__device__ __forceinline__ short f2bf(float f) {
  union { float f; unsigned u; } c; c.f = f;
  unsigned r = c.u + 0x7FFFu + ((c.u >> 16) & 1u);
  return (short)(r >> 16);
}
__device__ __forceinline__ float bf2f(short b) {
  union { unsigned u; float f; } c;
  c.u = ((unsigned)(unsigned short)b) << 16;
  return c.f;
}
__device__ __forceinline__ f32x4 mfma16(bf16x8 a, bf16x8 b, f32x4 c) {
  return __builtin_amdgcn_mfma_f32_16x16x32_bf16(a, b, c, 0, 0, 0);
}
__device__ __forceinline__ void gload16(const short* g, short* l) {
  __builtin_amdgcn_global_load_lds(
      (const __attribute__((address_space(1))) unsigned int*)g,
      (__attribute__((address_space(3))) unsigned int*)l, 16, 0, 0);
}

// ---------------- batched transpose + fp32->bf16 for four 1024x1024 weights ----------------
__global__ void k_transpose4(const float* __restrict__ w0, const float* __restrict__ w1,
                             const float* __restrict__ w2, const float* __restrict__ w3,
                             short* __restrict__ o0, short* __restrict__ o1,
                             short* __restrict__ o2, short* __restrict__ o3) {
  __shared__ float tile[32][33];
  int z = blockIdx.z;
  const float* in = (z == 0) ? w0 : (z == 1) ? w1 : (z == 2) ? w2 : w3;
  short* out = (z == 0) ? o0 : (z == 1) ? o1 : (z == 2) ? o2 : o3;
  int n0 = blockIdx.x * 32, k0 = blockIdx.y * 32;
  int tx = threadIdx.x & 31, ty = threadIdx.x >> 5;
  for (int i = ty; i < 32; i += 8) tile[i][tx] = in[(long)(k0 + i) * 1024 + n0 + tx];
  __syncthreads();
  for (int i = ty; i < 32; i += 8) out[(long)(n0 + i) * 1024 + k0 + tx] = f2bf(tile[tx][i]);
}

// ---------------- transpose + fp32->bf16 : out[N][K] = in[K][N] ----------------
__global__ void k_transpose_bf16(const float* __restrict__ in, short* __restrict__ out,
                                 int K, int N) {
  __shared__ float tile[32][33];
  int n0 = blockIdx.x * 32, k0 = blockIdx.y * 32;
  int tx = threadIdx.x & 31, ty = threadIdx.x >> 5;
  for (int i = ty; i < 32; i += 8) tile[i][tx] = in[(long)(k0 + i) * N + n0 + tx];
  __syncthreads();
  for (int i = ty; i < 32; i += 8) out[(long)(n0 + i) * K + k0 + tx] = f2bf(tile[tx][i]);
}

// ---------------- WbT[16][1024] = Wb[1024][16]^T (bf16) ----------------
__global__ void k_transpose_wb(const float* __restrict__ Wb, short* __restrict__ WbT) {
  int idx = blockIdx.x * 256 + threadIdx.x;
  int n = idx >> 10, k = idx & 1023;
  WbT[n * 1024 + k] = f2bf(Wb[k * 16 + n]);
}

// ---------------- mods = silu(c) @ W_ada + b_ada : 2-stage ----------------
__global__ void k_mods_p1(const float* __restrict__ c, const float* __restrict__ W_ada,
                          float* __restrict__ part) {
  int cx = blockIdx.x, dc = blockIdx.y, tid = threadIdx.x;
  __shared__ float s0[128], s1[128];
  if (tid < 128) {
    float v = c[dc * 128 + tid];
    s0[tid] = v / (1.f + expf(-v));
  } else {
    int t = tid - 128;
    float v = c[1024 + dc * 128 + t];
    s1[t] = v / (1.f + expf(-v));
  }
  __syncthreads();
  int col = cx * 256 + tid;
  float a0 = 0.f, a1 = 0.f;
  const float* wp = W_ada + (long)(dc * 128) * 6144 + col;
  for (int d = 0; d < 128; d++) {
    float w = wp[(long)d * 6144];
    a0 += s0[d] * w;
    a1 += s1[d] * w;
  }
  part[((long)dc * 2) * 6144 + col] = a0;
  part[((long)dc * 2 + 1) * 6144 + col] = a1;
}
__global__ void k_mods_p2(const float* __restrict__ part, const float* __restrict__ b_ada,
                          float* __restrict__ mods) {
  int col = blockIdx.x * 256 + threadIdx.x;
  float a0 = 0.f, a1 = 0.f;
  for (int dc = 0; dc < 8; dc++) {
    a0 += part[((long)dc * 2) * 6144 + col];
    a1 += part[((long)dc * 2 + 1) * 6144 + col];
  }
  float b = b_ada[col];
  mods[col] = a0 + b;
  mods[6144 + col] = a1 + b;
}

// ---------------- LayerNorm + modulate -> bf16 ----------------
__global__ void k_ln_mod(const float* __restrict__ x, const float* __restrict__ mods,
                         short* __restrict__ out, int sh_off, int sc_off) {
  int row = blockIdx.x, tid = threadIdx.x, b = row >> 11;
  float4 v = ((const float4*)(x + (long)row * 1024))[tid];
  float s = v.x + v.y + v.z + v.w;
  float ss = v.x * v.x + v.y * v.y + v.z * v.z + v.w * v.w;
  #pragma unroll
  for (int off = 1; off < 64; off <<= 1) { s += __shfl_xor(s, off); ss += __shfl_xor(ss, off); }
  __shared__ float rs[4], rq[4];
  if ((tid & 63) == 0) { rs[tid >> 6] = s; rq[tid >> 6] = ss; }
  __syncthreads();
  s = rs[0] + rs[1] + rs[2] + rs[3];
  ss = rq[0] + rq[1] + rq[2] + rq[3];
  float mu = s * (1.f / 1024.f);
  float rstd = rsqrtf(ss * (1.f / 1024.f) - mu * mu + 1e-6f);
  const float* shv = mods + b * 6144 + sh_off;
  const float* scv = mods + b * 6144 + sc_off;
  int c0 = tid * 4;
  float xs[4] = {v.x, v.y, v.z, v.w};
  s16x4 ov;
  #pragma unroll
  for (int j = 0; j < 4; j++)
    ov[j] = f2bf((xs[j] - mu) * rstd * (1.f + scv[c0 + j]) + shv[c0 + j]);
  ((s16x4*)(out + (long)row * 1024))[tid] = ov;
}

// ---------------- beta = sigmoid(xm @ WbT^T) via MFMA -> [4096][16] fp32 ----------------
__global__ __launch_bounds__(256) void k_beta_mfma(
    const short* __restrict__ xm, const short* __restrict__ WbT,
    float* __restrict__ beta) {
  int tid = threadIdx.x, w = tid >> 6, l = tid & 63;
  int lr = l & 15, lg = l >> 4;
  int row0 = blockIdx.x * 64 + w * 16;
  const short* ap = xm + (long)(row0 + lr) * 1024 + lg * 8;
  const short* bp = WbT + lr * 1024 + lg * 8;
  f32x4 acc = (f32x4){0.f, 0.f, 0.f, 0.f};
  #pragma unroll 8
  for (int kk = 0; kk < 1024; kk += 32) {
    bf16x8 a = *(const bf16x8*)(ap + kk);
    bf16x8 b = *(const bf16x8*)(bp + kk);
    acc = mfma16(a, b, acc);
  }
  #pragma unroll
  for (int i = 0; i < 4; i++) {
    int row = row0 + lg * 4 + i;
    beta[row * 16 + lr] = 1.f / (1.f + expf(-acc[i]));
  }
}

// ---- fused causal conv(4)+SiLU over all 3072 cols, bf16 in/out, l2norm q/k ----
__global__ __launch_bounds__(384) void k_conv3(
    const short* __restrict__ qkv, const float* __restrict__ wcq,
    const float* __restrict__ wck, const float* __restrict__ wcv,
    short* __restrict__ qbf, short* __restrict__ kb, short* __restrict__ vb) {
  int row = blockIdx.x, tid = threadIdx.x, t = row & 2047;
  int c0 = tid * 8;
  int seg = c0 >> 10;
  int lc = c0 & 1023;
  const float* wseg = (seg == 0) ? wcq : (seg == 1) ? wck : wcv;
  float xr[4][8];
  #pragma unroll
  for (int i = 0; i < 4; i++) {
    int tt = t - 3 + i;
    if (tt >= 0) {
      bf16x8 v = *(const bf16x8*)(qkv + (long)(row - 3 + i) * 3072 + c0);
      #pragma unroll
      for (int j = 0; j < 8; j++) xr[i][j] = bf2f(v[j]);
    } else {
      #pragma unroll
      for (int j = 0; j < 8; j++) xr[i][j] = 0.f;
    }
  }
  float y[8];
  #pragma unroll
  for (int j = 0; j < 8; j++) {
    float4 wv = *(const float4*)(wseg + (long)(lc + j) * 4);
    float a = xr[0][j] * wv.x + xr[1][j] * wv.y + xr[2][j] * wv.z + xr[3][j] * wv.w;
    y[j] = a / (1.f + __expf(-a));  // SiLU
  }
  if (seg < 2) {
    float ssq = 0.f;
    #pragma unroll
    for (int j = 0; j < 8; j++) ssq += y[j] * y[j];
    #pragma unroll
    for (int off = 1; off < 8; off <<= 1) ssq += __shfl_xor(ssq, off);
    float r = rsqrtf(ssq + 1e-6f) * ((seg == 0) ? 0.125f : 1.f);
    #pragma unroll
    for (int j = 0; j < 8; j++) y[j] *= r;
  }
  bf16x8 ov;
  #pragma unroll
  for (int j = 0; j < 8; j++) ov[j] = f2bf(y[j]);
  short* outp = (seg == 0) ? qbf : (seg == 1) ? kb : vb;
  *(bf16x8*)(outp + (long)row * 1024 + lc) = ov;
}

// ---------------- phase A (MFMA + blocked inverse), bf16 k/v inputs ----------------
__global__ __launch_bounds__(256) void k_phaseA(
    const short* __restrict__ kb, const short* __restrict__ vb,
    const short* __restrict__ qbf, const float* __restrict__ beta,
    short* __restrict__ Wc, short* __restrict__ UTc,
    short* __restrict__ Lc, short* __restrict__ KTc) {
  int chunk = blockIdx.x, chain = blockIdx.y;
  int b = chain >> 4, h = chain & 15;
  long rowbase = (long)b * 2048 + chunk * 64;
  int col0 = h * 64;
  long cb = ((long)chain * 32 + chunk) * 4096;
  __shared__ short Kb[64][72], KTb[64][72], VTb[64][72], Mb[64][72];
  __shared__ float Sf[64][65], Mf[64][65];
  __shared__ float Tl[4][16][20];
  __shared__ float bl[64];
  int tid = threadIdx.x, w = tid >> 6, l = tid & 63;
  int lr = l & 15, lg = l >> 4;

  for (int i = tid; i < 64 * 65; i += 256) (&Mf[0][0])[i] = 0.f;
  {
    int t = tid & 63, g = tid >> 6;
    if (tid < 64) bl[tid] = beta[(rowbase + tid) * 16 + h];
    int dk0 = g * 16;
    bf16x8 kv0 = *(const bf16x8*)(kb + (rowbase + t) * 1024 + col0 + dk0);
    bf16x8 kv1 = *(const bf16x8*)(kb + (rowbase + t) * 1024 + col0 + dk0 + 8);
    bf16x8 vv0 = *(const bf16x8*)(vb + (rowbase + t) * 1024 + col0 + dk0);
    bf16x8 vv1 = *(const bf16x8*)(vb + (rowbase + t) * 1024 + col0 + dk0 + 8);
    *(bf16x8*)&Kb[t][dk0] = kv0;
    *(bf16x8*)&Kb[t][dk0 + 8] = kv1;
    #pragma unroll
    for (int j = 0; j < 8; j++) {
      KTb[dk0 + j][t] = kv0[j];
      KTb[dk0 + 8 + j][t] = kv1[j];
      VTb[dk0 + j][t] = vv0[j];
      VTb[dk0 + 8 + j][t] = vv1[j];
    }
  }
  __syncthreads();
  {
    bf16x8 af0 = *(const bf16x8*)&Kb[w * 16 + lr][lg * 8];
    bf16x8 af1 = *(const bf16x8*)&Kb[w * 16 + lr][32 + lg * 8];
    #pragma unroll
    for (int nt = 0; nt < 4; nt++) {
      f32x4 acc = (f32x4){0.f, 0.f, 0.f, 0.f};
      acc = mfma16(af0, *(const bf16x8*)&Kb[nt * 16 + lr][lg * 8], acc);
      acc = mfma16(af1, *(const bf16x8*)&Kb[nt * 16 + lr][32 + lg * 8], acc);
      #pragma unroll
      for (int i = 0; i < 4; i++) {
        int row = w * 16 + lg * 4 + i, col = nt * 16 + lr;
        Sf[row][col] = (col < row) ? bl[row] * acc[i] : 0.f;
      }
    }
  }
  __syncthreads();
  if (w == 0) {
    int blk = l >> 4, colc = l & 15, base = blk * 16;
    float mcol[16];
    #pragma unroll
    for (int r = 0; r < 16; r++) {
      float s = (r == colc) ? 1.f : 0.f;
      #pragma unroll
      for (int j = 0; j < 16; j++)
        if (j < r) s -= Sf[base + r][base + j] * mcol[j];
      mcol[r] = s;
    }
    #pragma unroll
    for (int r = 0; r < 16; r++) Mf[base + r][base + colc] = mcol[r];
  } else if (w <= 2) {
    int idx = (w - 1) * 64 + l;
    #pragma unroll
    for (int i = 0; i < 4; i++) {
      int v = idx * 4 + i, row = v >> 3, cg = (v & 7) * 8;
      *(bf16x8*)&KTc[cb + row * 64 + cg] = *(const bf16x8*)&KTb[row][cg];
    }
  }
  __syncthreads();
  if (w < 3) {
    int j = w;
    int r = l & 15, c4 = (l >> 4) * 4;
    for (int i = j + 1; i < 4; i++) {
      float t4[4] = {0.f, 0.f, 0.f, 0.f};
      for (int k = j; k < i; k++) {
        #pragma unroll
        for (int m = 0; m < 16; m++) {
          float a = Sf[i * 16 + r][k * 16 + m];
          #pragma unroll
          for (int ii = 0; ii < 4; ii++)
            t4[ii] += a * Mf[k * 16 + m][j * 16 + c4 + ii];
        }
      }
      #pragma unroll
      for (int ii = 0; ii < 4; ii++) Tl[w][r][c4 + ii] = t4[ii];
      float o4[4] = {0.f, 0.f, 0.f, 0.f};
      #pragma unroll
      for (int m = 0; m < 16; m++) {
        float d = Mf[i * 16 + r][i * 16 + m];
        #pragma unroll
        for (int ii = 0; ii < 4; ii++) o4[ii] += d * Tl[w][m][c4 + ii];
      }
      #pragma unroll
      for (int ii = 0; ii < 4; ii++) Mf[i * 16 + r][j * 16 + c4 + ii] = -o4[ii];
    }
  }
  __syncthreads();
  {
    int r = tid >> 2, c0 = (tid & 3) * 16;
    #pragma unroll
    for (int j2 = 0; j2 < 16; j2++)
      Mb[r][c0 + j2] = f2bf(Mf[r][c0 + j2] * bl[c0 + j2]);
  }
  __syncthreads();
  {
    bf16x8 am0 = *(const bf16x8*)&Mb[w * 16 + lr][lg * 8];
    bf16x8 am1 = *(const bf16x8*)&Mb[w * 16 + lr][32 + lg * 8];
    bf16x8 av0 = *(const bf16x8*)&VTb[w * 16 + lr][lg * 8];
    bf16x8 av1 = *(const bf16x8*)&VTb[w * 16 + lr][32 + lg * 8];
    long qoff = (rowbase + w * 16 + lr) * 1024 + col0 + lg * 8;
    bf16x8 aq0 = *(const bf16x8*)&qbf[qoff];
    bf16x8 aq1 = *(const bf16x8*)&qbf[qoff + 32];
    #pragma unroll
    for (int nt = 0; nt < 4; nt++) {
      f32x4 wa = (f32x4){0.f, 0.f, 0.f, 0.f};
      f32x4 ua = (f32x4){0.f, 0.f, 0.f, 0.f};
      f32x4 la = (f32x4){0.f, 0.f, 0.f, 0.f};
      wa = mfma16(am0, *(const bf16x8*)&KTb[nt * 16 + lr][lg * 8], wa);
      wa = mfma16(am1, *(const bf16x8*)&KTb[nt * 16 + lr][32 + lg * 8], wa);
      ua = mfma16(av0, *(const bf16x8*)&Mb[nt * 16 + lr][lg * 8], ua);
      ua = mfma16(av1, *(const bf16x8*)&Mb[nt * 16 + lr][32 + lg * 8], ua);
      la = mfma16(aq0, *(const bf16x8*)&Kb[nt * 16 + lr][lg * 8], la);
      la = mfma16(aq1, *(const bf16x8*)&Kb[nt * 16 + lr][32 + lg * 8], la);
      #pragma unroll
      for (int i = 0; i < 4; i++) {
        int row = w * 16 + lg * 4 + i, col = nt * 16 + lr;
        Wc[cb + row * 64 + col] = f2bf(wa[i]);
        UTc[cb + row * 64 + col] = f2bf(ua[i]);
        Lc[cb + row * 64 + col] = f2bf((col <= row) ? la[i] : 0.f);
      }
    }
  }
}

// ---------------- phase B sequential: state scan only, dv-sliced ----------------
__global__ __launch_bounds__(256) void k_phaseB_seq(
    const short* __restrict__ Wc, const short* __restrict__ UTc,
    const short* __restrict__ KTc, short* __restrict__ STb, short* __restrict__ DTb) {
  int ds = blockIdx.x, chain = blockIdx.y;
  __shared__ short Wl[2][64][72];
  __shared__ short Kl[2][64][72];
  __shared__ short Ul[2][16][72];
  __shared__ float STf[16][68];
  __shared__ short Sb[16][72];
  __shared__ short DTl[16][72];
  int tid = threadIdx.x, w = tid >> 6, l = tid & 63;
  int lr = l & 15, lg = l >> 4;
  for (int i = tid; i < 16 * 68; i += 256) (&STf[0][0])[i] = 0.f;
  for (int i = tid; i < 16 * 72; i += 256) (&Sb[0][0])[i] = 0;
  int srow = tid >> 2, scol = (tid & 3) * 16;
  int ur = tid >> 4, uc = (tid & 15) * 4;
  bf16x8 wreg0, wreg1, kreg0, kreg1;
  s16x4 ureg;
  {
    long cb = (long)chain * 32 * 4096;
    wreg0 = *(const bf16x8*)&Wc[cb + srow * 64 + scol];
    wreg1 = *(const bf16x8*)&Wc[cb + srow * 64 + scol + 8];
    kreg0 = *(const bf16x8*)&KTc[cb + srow * 64 + scol];
    kreg1 = *(const bf16x8*)&KTc[cb + srow * 64 + scol + 8];
    ureg  = *(const s16x4*)&UTc[cb + (ds * 16 + ur) * 64 + uc];
  }
  *(bf16x8*)&Wl[0][srow][scol] = wreg0;
  *(bf16x8*)&Wl[0][srow][scol + 8] = wreg1;
  *(bf16x8*)&Kl[0][srow][scol] = kreg0;
  *(bf16x8*)&Kl[0][srow][scol + 8] = kreg1;
  *(s16x4*)&Ul[0][ur][uc] = ureg;
  __syncthreads();
  int cur = 0;
  for (int c = 0; c < 32; c++) {
    if (c + 1 < 32) {
      long cb = ((long)chain * 32 + c + 1) * 4096;
      wreg0 = *(const bf16x8*)&Wc[cb + srow * 64 + scol];
      wreg1 = *(const bf16x8*)&Wc[cb + srow * 64 + scol + 8];
      kreg0 = *(const bf16x8*)&KTc[cb + srow * 64 + scol];
      kreg1 = *(const bf16x8*)&KTc[cb + srow * 64 + scol + 8];
      ureg  = *(const s16x4*)&UTc[cb + (ds * 16 + ur) * 64 + uc];
    }
    {
      long so = (((long)chain * 32 + c) * 64 + ds * 16 + ur) * 64 + uc;
      *(s16x4*)&STb[so] = *(const s16x4*)&Sb[ur][uc];
    }
    bf16x8 afr0 = *(const bf16x8*)&Sb[lr][lg * 8];
    bf16x8 afr1 = *(const bf16x8*)&Sb[lr][32 + lg * 8];
    f32x4 dacc = (f32x4){0.f, 0.f, 0.f, 0.f};
    dacc = mfma16(afr0, *(const bf16x8*)&Wl[cur][w * 16 + lr][lg * 8], dacc);
    dacc = mfma16(afr1, *(const bf16x8*)&Wl[cur][w * 16 + lr][32 + lg * 8], dacc);
    #pragma unroll
    for (int i = 0; i < 4; i++) {
      int dv = lg * 4 + i, tt = w * 16 + lr;
      float u = bf2f(Ul[cur][dv][tt]);
      short d = f2bf(u - dacc[i]);
      DTl[dv][tt] = d;
      DTb[(((long)chain * 32 + c) * 64 + ds * 16 + dv) * 64 + tt] = d;
    }
    __syncthreads();
    bf16x8 ad0 = *(const bf16x8*)&DTl[lr][lg * 8];
    bf16x8 ad1 = *(const bf16x8*)&DTl[lr][32 + lg * 8];
    f32x4 sacc;
    #pragma unroll
    for (int i = 0; i < 4; i++) sacc[i] = STf[lg * 4 + i][w * 16 + lr];
    sacc = mfma16(ad0, *(const bf16x8*)&Kl[cur][w * 16 + lr][lg * 8], sacc);
    sacc = mfma16(ad1, *(const bf16x8*)&Kl[cur][w * 16 + lr][32 + lg * 8], sacc);
    #pragma unroll
    for (int i = 0; i < 4; i++) {
      STf[lg * 4 + i][w * 16 + lr] = sacc[i];
      Sb[lg * 4 + i][w * 16 + lr] = f2bf(sacc[i]);
    }
    __syncthreads();
    if (c + 1 < 32) {
      int nxt = cur ^ 1;
      *(bf16x8*)&Wl[nxt][srow][scol] = wreg0;
      *(bf16x8*)&Wl[nxt][srow][scol + 8] = wreg1;
      *(bf16x8*)&Kl[nxt][srow][scol] = kreg0;
      *(bf16x8*)&Kl[nxt][srow][scol + 8] = kreg1;
      *(s16x4*)&Ul[nxt][ur][uc] = ureg;
      cur = nxt;
      __syncthreads();
    }
  }
}

// ---------------- phase B parallel: O = Q S_c + L D_c, fused per-head RMSNorm ----------------
__global__ __launch_bounds__(256) void k_phaseBo(
    const short* __restrict__ STb, const short* __restrict__ DTb,
    const short* __restrict__ Lc, const short* __restrict__ qbf,
    const float* __restrict__ wn, short* __restrict__ on) {
  int chunk = blockIdx.x, chain = blockIdx.y;
  int b = chain >> 4, h = chain & 15;
  int tid = threadIdx.x, w = tid >> 6, l = tid & 63;
  int lr = l & 15, lg = l >> 4;
  long cb = ((long)chain * 32 + chunk) * 4096;
  long rowbase = (long)b * 2048 + chunk * 64;
  bf16x8 aq[2], alf[2];
  long qoff = (rowbase + w * 16 + lr) * 1024 + h * 64 + lg * 8;
  aq[0] = *(const bf16x8*)&qbf[qoff];
  aq[1] = *(const bf16x8*)&qbf[qoff + 32];
  alf[0] = *(const bf16x8*)&Lc[cb + (w * 16 + lr) * 64 + lg * 8];
  alf[1] = *(const bf16x8*)&Lc[cb + (w * 16 + lr) * 64 + 32 + lg * 8];
  f32x4 oacc[4];
  #pragma unroll
  for (int nt = 0; nt < 4; nt++) {
    oacc[nt] = (f32x4){0.f, 0.f, 0.f, 0.f};
    #pragma unroll
    for (int kk = 0; kk < 2; kk++) {
      bf16x8 bs = *(const bf16x8*)&STb[cb + (nt * 16 + lr) * 64 + kk * 32 + lg * 8];
      oacc[nt] = mfma16(aq[kk], bs, oacc[nt]);
      bf16x8 bd = *(const bf16x8*)&DTb[cb + (nt * 16 + lr) * 64 + kk * 32 + lg * 8];
      oacc[nt] = mfma16(alf[kk], bd, oacc[nt]);
    }
  }
  float ss[4];
  #pragma unroll
  for (int i = 0; i < 4; i++) {
    ss[i] = 0.f;
    #pragma unroll
    for (int nt = 0; nt < 4; nt++) ss[i] += oacc[nt][i] * oacc[nt][i];
  }
  #pragma unroll
  for (int off = 1; off < 16; off <<= 1) {
    #pragma unroll
    for (int i = 0; i < 4; i++) ss[i] += __shfl_xor(ss[i], off);
  }
  float rr[4];
  #pragma unroll
  for (int i = 0; i < 4; i++) rr[i] = rsqrtf(ss[i] * (1.f / 64.f) + 1e-6f);
  float wnv[4];
  #pragma unroll
  for (int nt = 0; nt < 4; nt++) wnv[nt] = wn[nt * 16 + lr];
  #pragma unroll
  for (int nt = 0; nt < 4; nt++) {
    #pragma unroll
    for (int i = 0; i < 4; i++) {
      long orow = rowbase + w * 16 + lg * 4 + i;
      on[orow * 1024 + h * 64 + nt * 16 + lr] = f2bf(oacc[nt][i] * rr[i] * wnv[nt]);
    }
  }
}

// ---- shared GEMM epilogue ----
template <int EPI>
__device__ __forceinline__ void gemm_epi(float v, int row, int col, int N, void* C,
                                         const float* P1, const float* P2, const float* P3) {
  if (EPI == 0) {
    ((float*)C)[(long)row * N + col] = v;
  } else if (EPI == 1) {
    int bb = row >> 11;
    ((float*)C)[(long)row * N + col] = P1[(long)row * N + col] + P2[bb * 6144 + 2048 + col] * v;
  } else if (EPI == 2) {
    float t = v + P1[col];
    float y = 1.5957691216f * (t + 0.044715f * t * t * t);
    float g = t / (1.f + __expf(-y));
    ((short*)C)[(long)row * N + col] = f2bf(g);
  } else if (EPI == 3) {
    int bb = row >> 11;
    ((float*)C)[(long)row * N + col] =
        P1[(long)row * 1024 + col] + P2[bb * 6144 + 5120 + col] * (v + P3[col]);
  } else {
    ((short*)C)[(long)row * N + col] = f2bf(v);
  }
}

// --- 128x128 single-buffer m97-shape GEMM: 256 thr, 4 waves (2x2, 64x64/wave),
// acc[4][4], 32KB LDS, T2 swizzle, T1 block swizzle. Best for cheap-epilogue
// GEMMs at >=3 blocks/CU (QKV).
template <int EPI>
__global__ __launch_bounds__(256) void k_gemm128m(
    const short* __restrict__ A, const short* __restrict__ BT, void* __restrict__ C,
    int M, int N, int K,
    const float* __restrict__ P1, const float* __restrict__ P2, const float* __restrict__ P3) {
  __shared__ short As[128 * 64];
  __shared__ short Bs[128 * 64];
  int tid = threadIdx.x, w = tid >> 6, l = tid & 63;
  int lr = l & 15, lg = l >> 4;
  int wr = w >> 1, wc = w & 1;
  int nx = gridDim.x;
  int orig = blockIdx.y * nx + blockIdx.x;
  int cpx = (nx * gridDim.y) >> 3;
  int swz = (orig & 7) * cpx + (orig >> 3);
  int bx = swz % nx, by = swz / nx;
  int row0 = by * 128, col0 = bx * 128;
  int scol = ((l & 7) ^ (l >> 3)) * 8;
  const short* Ab = A + (long)(row0 + w * 8 + (l >> 3)) * K + scol;
  const short* Bb = BT + (long)(col0 + w * 8 + (l >> 3)) * K + scol;
  f32x4 acc[4][4];
  #pragma unroll
  for (int m = 0; m < 4; m++)
    #pragma unroll
    for (int n = 0; n < 4; n++) acc[m][n] = (f32x4){0.f, 0.f, 0.f, 0.f};
  int u0 = ((0 + lg) ^ (lr & 7)) * 8;
  int u1 = ((4 + lg) ^ (lr & 7)) * 8;

  for (int kt = 0; kt < K; kt += 64) {
    #pragma unroll
    for (int i = 0; i < 4; i++) {
      gload16(Ab + (long)i * 32 * K + kt, &As[(i * 32 + w * 8) * 64]);
      gload16(Bb + (long)i * 32 * K + kt, &Bs[(i * 32 + w * 8) * 64]);
    }
    __syncthreads();
    {
      bf16x8 af[4], bv[4];
      #pragma unroll
      for (int m = 0; m < 4; m++)
        af[m] = *(const bf16x8*)&As[(wr * 64 + m * 16 + lr) * 64 + u0];
      #pragma unroll
      for (int n = 0; n < 4; n++)
        bv[n] = *(const bf16x8*)&Bs[(wc * 64 + n * 16 + lr) * 64 + u0];
      #pragma unroll
      for (int m = 0; m < 4; m++)
        #pragma unroll
        for (int n = 0; n < 4; n++)
          acc[m][n] = mfma16(af[m], bv[n], acc[m][n]);
      #pragma unroll
      for (int m = 0; m < 4; m++)
        af[m] = *(const bf16x8*)&As[(wr * 64 + m * 16 + lr) * 64 + u1];
      #pragma unroll
      for (int n = 0; n < 4; n++)
        bv[n] = *(const bf16x8*)&Bs[(wc * 64 + n * 16 + lr) * 64 + u1];
      #pragma unroll
      for (int m = 0; m < 4; m++)
        #pragma unroll
        for (int n = 0; n < 4; n++)
          acc[m][n] = mfma16(af[m], bv[n], acc[m][n]);
    }
    __syncthreads();
  }

  #pragma unroll
  for (int m = 0; m < 4; m++)
    #pragma unroll
    for (int n = 0; n < 4; n++) {
      int col = col0 + wc * 64 + n * 16 + lr;
      #pragma unroll
      for (int i = 0; i < 4; i++)
        gemm_epi<EPI>(acc[m][n][i], row0 + wr * 64 + m * 16 + lg * 4 + i, col, N, C, P1, P2, P3);
    }
}

// --- 128x128 single-buffer 8-wave GEMM (2Mx4N, 64x32/wave): 32KB LDS ->
// 4 blocks/CU wave-capped. Best for W1 (heavier gelu epilogue spread over 512 thr).
template <int EPI>
__global__ __launch_bounds__(512, 4) void k_gemm128s(
    const short* __restrict__ A, const short* __restrict__ BT, void* __restrict__ C,
    int M, int N, int K,
    const float* __restrict__ P1, const float* __restrict__ P2, const float* __restrict__ P3) {
  __shared__ short As[128 * 64];
  __shared__ short Bs[128 * 64];
  int tid = threadIdx.x, w = tid >> 6, l = tid & 63;
  int lr = l & 15, lg = l >> 4;
  int wr = w >> 2, wc = w & 3;
  int nx = gridDim.x;
  int orig = blockIdx.y * nx + blockIdx.x;
  int cpx = (nx * gridDim.y) >> 3;
  int swz = (orig & 7) * cpx + (orig >> 3);
  int bx = swz % nx, by = swz / nx;
  int row0 = by * 128, col0 = bx * 128;
  int scol = ((l & 7) ^ (l >> 3)) * 8;
  const short* Ab = A + (long)(row0 + w * 8 + (l >> 3)) * K + scol;
  const short* Bb = BT + (long)(col0 + w * 8 + (l >> 3)) * K + scol;
  f32x4 acc[4][2];
  #pragma unroll
  for (int m = 0; m < 4; m++)
    #pragma unroll
    for (int n = 0; n < 2; n++) acc[m][n] = (f32x4){0.f, 0.f, 0.f, 0.f};
  int u0 = ((0 + lg) ^ (lr & 7)) * 8;
  int u1 = ((4 + lg) ^ (lr & 7)) * 8;

  for (int kt = 0; kt < K; kt += 64) {
    #pragma unroll
    for (int i = 0; i < 2; i++) {
      gload16(Ab + (long)i * 64 * K + kt, &As[(i * 64 + w * 8) * 64]);
      gload16(Bb + (long)i * 64 * K + kt, &Bs[(i * 64 + w * 8) * 64]);
    }
    __syncthreads();
    {
      bf16x8 af[4], bv[2];
      #pragma unroll
      for (int m = 0; m < 4; m++)
        af[m] = *(const bf16x8*)&As[(wr * 64 + m * 16 + lr) * 64 + u0];
      #pragma unroll
      for (int n = 0; n < 2; n++)
        bv[n] = *(const bf16x8*)&Bs[(wc * 32 + n * 16 + lr) * 64 + u0];
      #pragma unroll
      for (int m = 0; m < 4; m++)
        #pragma unroll
        for (int n = 0; n < 2; n++)
          acc[m][n] = mfma16(af[m], bv[n], acc[m][n]);
      #pragma unroll
      for (int m = 0; m < 4; m++)
        af[m] = *(const bf16x8*)&As[(wr * 64 + m * 16 + lr) * 64 + u1];
      #pragma unroll
      for (int n = 0; n < 2; n++)
        bv[n] = *(const bf16x8*)&Bs[(wc * 32 + n * 16 + lr) * 64 + u1];
      #pragma unroll
      for (int m = 0; m < 4; m++)
        #pragma unroll
        for (int n = 0; n < 2; n++)
          acc[m][n] = mfma16(af[m], bv[n], acc[m][n]);
    }
    __syncthreads();
  }

  #pragma unroll
  for (int m = 0; m < 4; m++)
    #pragma unroll
    for (int n = 0; n < 2; n++) {
      int col = col0 + wc * 32 + n * 16 + lr;
      #pragma unroll
      for (int i = 0; i < 4; i++)
        gemm_epi<EPI>(acc[m][n][i], row0 + wr * 64 + m * 16 + lg * 4 + i, col, N, C, P1, P2, P3);
    }
}

// --- 64x128-tile dbuf bf16 MFMA GEMM, 8 waves (2Mx4N, 32x32/wave), T2+T1 ---
// 48KB LDS -> 2 blocks/CU; for grid-capped N=1024 GEMMs (Wo/W2: 512 blocks).
template <int EPI>
__global__ __launch_bounds__(512, 4) void k_gemm64(
    const short* __restrict__ A, const short* __restrict__ BT, void* __restrict__ C,
    int M, int N, int K,
    const float* __restrict__ P1, const float* __restrict__ P2, const float* __restrict__ P3) {
  __shared__ short As[2][64 * 64];
  __shared__ short Bs[2][128 * 64];
  int tid = threadIdx.x, w = tid >> 6, l = tid & 63;
  int lr = l & 15, lg = l >> 4;
  int wr = w >> 2, wc = w & 3;
  int nx = gridDim.x;
  int orig = blockIdx.y * nx + blockIdx.x;
  int cpx = (nx * gridDim.y) >> 3;
  int swz = (orig & 7) * cpx + (orig >> 3);
  int bx = swz % nx, by = swz / nx;
  int row0 = by * 64, col0 = bx * 128;
  int scol = ((l & 7) ^ (l >> 3)) * 8;
  const short* Ab = A + (long)(row0 + w * 8 + (l >> 3)) * K + scol;
  const short* Bb = BT + (long)(col0 + w * 8 + (l >> 3)) * K + scol;
  f32x4 acc[2][2];
  #pragma unroll
  for (int m = 0; m < 2; m++)
    #pragma unroll
    for (int n = 0; n < 2; n++) acc[m][n] = (f32x4){0.f, 0.f, 0.f, 0.f};
  int u0 = ((0 + lg) ^ (lr & 7)) * 8;
  int u1 = ((4 + lg) ^ (lr & 7)) * 8;

#define STAGE_S(buf, kt)                                                        \
  {                                                                             \
    gload16(Ab + (kt), &As[buf][(w * 8) * 64]);                                 \
    _Pragma("unroll") for (int i = 0; i < 2; i++)                               \
      gload16(Bb + (long)i * 64 * K + (kt), &Bs[buf][(i * 64 + w * 8) * 64]);   \
  }
#define COMPUTE_S(buf)                                                          \
  {                                                                             \
    bf16x8 af[2], bv[2];                                                        \
    _Pragma("unroll") for (int m = 0; m < 2; m++)                               \
      af[m] = *(const bf16x8*)&As[buf][(wr * 32 + m * 16 + lr) * 64 + u0];      \
    _Pragma("unroll") for (int n = 0; n < 2; n++)                               \
      bv[n] = *(const bf16x8*)&Bs[buf][(wc * 32 + n * 16 + lr) * 64 + u0];      \
    _Pragma("unroll") for (int m = 0; m < 2; m++)                               \
      _Pragma("unroll") for (int n = 0; n < 2; n++)                             \
        acc[m][n] = mfma16(af[m], bv[n], acc[m][n]);                            \
    _Pragma("unroll") for (int m = 0; m < 2; m++)                               \
      af[m] = *(const bf16x8*)&As[buf][(wr * 32 + m * 16 + lr) * 64 + u1];      \
    _Pragma("unroll") for (int n = 0; n < 2; n++)                               \
      bv[n] = *(const bf16x8*)&Bs[buf][(wc * 32 + n * 16 + lr) * 64 + u1];      \
    _Pragma("unroll") for (int m = 0; m < 2; m++)                               \
      _Pragma("unroll") for (int n = 0; n < 2; n++)                             \
        acc[m][n] = mfma16(af[m], bv[n], acc[m][n]);                            \
  }

  STAGE_S(0, 0);
  __syncthreads();
  int cur = 0;
  int ktLast = K - 64;
  for (int kt = 0; kt < ktLast; kt += 64) {
    STAGE_S(cur ^ 1, kt + 64);
    COMPUTE_S(cur);
    __syncthreads();
    cur ^= 1;
  }
  COMPUTE_S(cur);
#undef STAGE_S
#undef COMPUTE_S

  #pragma unroll
  for (int m = 0; m < 2; m++)
    #pragma unroll
    for (int n = 0; n < 2; n++) {
      int col = col0 + wc * 32 + n * 16 + lr;
      #pragma unroll
      for (int i = 0; i < 4; i++)
        gemm_epi<EPI>(acc[m][n][i], row0 + wr * 32 + m * 16 + lg * 4 + i, col, N, C, P1, P2, P3);
    }
}

// ---------------- workspace layout (bytes) ----------------
#define OFF_MODS  0L
#define OFF_MODSP 49152L
#define OFF_XM    442368L
#define OFF_QKV   8830976L
#define OFF_QBF   59162624L
#define OFF_KF    67551232L
#define OFF_VF    84328448L
#define OFF_BETA  101105664L
#define OFF_WC    101367808L
#define OFF_UT    109756416L
#define OFF_LC    118145024L
#define OFF_KT    126533632L
#define OFF_ON    134922240L
#define OFF_X2    143310848L
#define OFF_WQT   160088064L
#define OFF_WKT   162185216L
#define OFF_WVT   164282368L
#define OFF_WOT   166379520L
#define OFF_W1T   168476672L
#define OFF_W2T   176865280L
#define OFF_WBT   185253888L
#define OFF_STB   OFF_QKV
#define OFF_DTB   (OFF_QKV + 8388608L)
#define OFF_M1    (OFF_QKV + 16777216L)
#define OFF_H     OFF_XM

extern "C" void kernel_launch(void* const* d_in, const int* in_sizes, int n_in,
                              void* d_out, int out_size, void* d_ws, size_t ws_size,
                              hipStream_t stream) {
  const float* x     = (const float*)d_in[0];
  const float* c     = (const float*)d_in[1];
  const float* W_ada = (const float*)d_in[2];
  const float* b_ada = (const float*)d_in[3];
  const float* Wq    = (const float*)d_in[4];
  const float* Wk    = (const float*)d_in[5];
  const float* Wv    = (const float*)d_in[6];
  const float* Wb    = (const float*)d_in[7];
  const float* wcq   = (const float*)d_in[8];
  const float* wck   = (const float*)d_in[9];
  const float* wcv   = (const float*)d_in[10];
  const float* wn    = (const float*)d_in[11];
  const float* Wo    = (const float*)d_in[12];
  const float* W1    = (const float*)d_in[13];
  const float* b1    = (const float*)d_in[14];
  const float* W2    = (const float*)d_in[15];
  const float* b2    = (const float*)d_in[16];
  float* out = (float*)d_out;
  char* ws = (char*)d_ws;

  float* mods = (float*)(ws + OFF_MODS);
  float* modp = (float*)(ws + OFF_MODSP);
  short* xm   = (short*)(ws + OFF_XM);
  short* qkv  = (short*)(ws + OFF_QKV);
  short* qbf  = (short*)(ws + OFF_QBF);
  short* kb   = (short*)(ws + OFF_KF);
  short* vb   = (short*)(ws + OFF_VF);
  float* beta = (float*)(ws + OFF_BETA);
  short* Wc   = (short*)(ws + OFF_WC);
  short* UTc  = (short*)(ws + OFF_UT);
  short* Lc   = (short*)(ws + OFF_LC);
  short* KTc  = (short*)(ws + OFF_KT);
  short* STb  = (short*)(ws + OFF_STB);
  short* DTb  = (short*)(ws + OFF_DTB);
  short* on   = (short*)(ws + OFF_ON);
  float* x2   = (float*)(ws + OFF_X2);
  short* hbuf = (short*)(ws + OFF_H);
  short* m1   = (short*)(ws + OFF_M1);
  short* WqT  = (short*)(ws + OFF_WQT);
  short* WkT  = (short*)(ws + OFF_WKT);
  short* WvT  = (short*)(ws + OFF_WVT);
  short* WoT  = (short*)(ws + OFF_WOT);
  short* W1T  = (short*)(ws + OFF_W1T);
  short* W2T  = (short*)(ws + OFF_W2T);
  short* WbT  = (short*)(ws + OFF_WBT);

  k_transpose4<<<dim3(32, 32, 4), 256, 0, stream>>>(Wq, Wk, Wv, Wo, WqT, WkT, WvT, WoT);
  k_transpose_bf16<<<dim3(128, 32), 256, 0, stream>>>(W1, W1T, 1024, 4096);
  k_transpose_bf16<<<dim3(32, 128), 256, 0, stream>>>(W2, W2T, 4096, 1024);
  k_transpose_wb<<<64, 256, 0, stream>>>(Wb, WbT);

  k_mods_p1<<<dim3(24, 8), 256, 0, stream>>>(c, W_ada, modp);
  k_mods_p2<<<24, 256, 0, stream>>>(modp, b_ada, mods);
  k_ln_mod<<<4096, 256, 0, stream>>>(x, mods, xm, 0, 1024);

  k_gemm128m<4><<<dim3(24, 32), 256, 0, stream>>>(xm, WqT, qkv, 4096, 3072, 1024,
                                                  nullptr, nullptr, nullptr);
  k_beta_mfma<<<64, 256, 0, stream>>>(xm, WbT, beta);

  k_conv3<<<4096, 384, 0, stream>>>(qkv, wcq, wck, wcv, qbf, kb, vb);

  k_phaseA<<<dim3(32, 32), 256, 0, stream>>>(kb, vb, qbf, beta, Wc, UTc, Lc, KTc);
  k_phaseB_seq<<<dim3(4, 32), 256, 0, stream>>>(Wc, UTc, KTc, STb, DTb);
  k_phaseBo<<<dim3(32, 32), 256, 0, stream>>>(STb, DTb, Lc, qbf, wn, on);

  k_gemm64<1><<<dim3(8, 64), 512, 0, stream>>>(on, WoT, x2, 4096, 1024, 1024,
                                               x, mods, nullptr);

  k_ln_mod<<<4096, 256, 0, stream>>>(x2, mods, hbuf, 3072, 4096);
  k_gemm128s<2><<<dim3(32, 32), 512, 0, stream>>>(hbuf, W1T, m1, 4096, 4096, 1024,
                                                  b1, nullptr, nullptr);
  k_gemm64<3><<<dim3(8, 64), 512, 0, stream>>>(m1, W2T, out, 4096, 1024, 4096,
                                               x2, mods, b2);
}

// Round 17
// 299.217 us; speedup vs baseline: 1.0667x; 1.0667x over previous
//
#include <hip/hip_runtime.h>
#include <math.h>

typedef __attribute__((ext_vector_type(4))) float f32x4;
typedef __attribute__((ext_vector_type(8))) short bf16x8;
typedef __attribute__((ext_vector_type(4))) short s16x4;

__device__ __forceinline__ short f2bf(float f) {
  union { float f; unsigned u; } c; c.f = f;
  unsigned r = c.u + 0x7FFFu + ((c.u >> 16) & 1u);
  return (short)(r >> 16);
}
__device__ __forceinline__ float bf2f(short b) {
  union { unsigned u; float f; } c;
  c.u = ((unsigned)(unsigned short)b) << 16;
  return c.f;
}
__device__ __forceinline__ f32x4 mfma16(bf16x8 a, bf16x8 b, f32x4 c) {
  return __builtin_amdgcn_mfma_f32_16x16x32_bf16(a, b, c, 0, 0, 0);
}
__device__ __forceinline__ void gload16(const short* g, short* l) {
  __builtin_amdgcn_global_load_lds(
      (const __attribute__((address_space(1))) unsigned int*)g,
      (__attribute__((address_space(3))) unsigned int*)l, 16, 0, 0);
}

// ---------------- batched transpose + fp32->bf16 for four 1024x1024 weights ----------------
__global__ void k_transpose4(const float* __restrict__ w0, const float* __restrict__ w1,
                             const float* __restrict__ w2, const float* __restrict__ w3,
                             short* __restrict__ o0, short* __restrict__ o1,
                             short* __restrict__ o2, short* __restrict__ o3) {
  __shared__ float tile[32][33];
  int z = blockIdx.z;
  const float* in = (z == 0) ? w0 : (z == 1) ? w1 : (z == 2) ? w2 : w3;
  short* out = (z == 0) ? o0 : (z == 1) ? o1 : (z == 2) ? o2 : o3;
  int n0 = blockIdx.x * 32, k0 = blockIdx.y * 32;
  int tx = threadIdx.x & 31, ty = threadIdx.x >> 5;
  for (int i = ty; i < 32; i += 8) tile[i][tx] = in[(long)(k0 + i) * 1024 + n0 + tx];
  __syncthreads();
  for (int i = ty; i < 32; i += 8) out[(long)(n0 + i) * 1024 + k0 + tx] = f2bf(tile[tx][i]);
}

// ---------------- transpose + fp32->bf16 : out[N][K] = in[K][N] ----------------
__global__ void k_transpose_bf16(const float* __restrict__ in, short* __restrict__ out,
                                 int K, int N) {
  __shared__ float tile[32][33];
  int n0 = blockIdx.x * 32, k0 = blockIdx.y * 32;
  int tx = threadIdx.x & 31, ty = threadIdx.x >> 5;
  for (int i = ty; i < 32; i += 8) tile[i][tx] = in[(long)(k0 + i) * N + n0 + tx];
  __syncthreads();
  for (int i = ty; i < 32; i += 8) out[(long)(n0 + i) * K + k0 + tx] = f2bf(tile[tx][i]);
}

// ---------------- WbT[16][1024] = Wb[1024][16]^T (bf16) ----------------
__global__ void k_transpose_wb(const float* __restrict__ Wb, short* __restrict__ WbT) {
  int idx = blockIdx.x * 256 + threadIdx.x;
  int n = idx >> 10, k = idx & 1023;
  WbT[n * 1024 + k] = f2bf(Wb[k * 16 + n]);
}

// ---------------- mods = silu(c) @ W_ada + b_ada : 2-stage ----------------
__global__ void k_mods_p1(const float* __restrict__ c, const float* __restrict__ W_ada,
                          float* __restrict__ part) {
  int cx = blockIdx.x, dc = blockIdx.y, tid = threadIdx.x;
  __shared__ float s0[128], s1[128];
  if (tid < 128) {
    float v = c[dc * 128 + tid];
    s0[tid] = v / (1.f + expf(-v));
  } else {
    int t = tid - 128;
    float v = c[1024 + dc * 128 + t];
    s1[t] = v / (1.f + expf(-v));
  }
  __syncthreads();
  int col = cx * 256 + tid;
  float a0 = 0.f, a1 = 0.f;
  const float* wp = W_ada + (long)(dc * 128) * 6144 + col;
  for (int d = 0; d < 128; d++) {
    float w = wp[(long)d * 6144];
    a0 += s0[d] * w;
    a1 += s1[d] * w;
  }
  part[((long)dc * 2) * 6144 + col] = a0;
  part[((long)dc * 2 + 1) * 6144 + col] = a1;
}
__global__ void k_mods_p2(const float* __restrict__ part, const float* __restrict__ b_ada,
                          float* __restrict__ mods) {
  int col = blockIdx.x * 256 + threadIdx.x;
  float a0 = 0.f, a1 = 0.f;
  for (int dc = 0; dc < 8; dc++) {
    a0 += part[((long)dc * 2) * 6144 + col];
    a1 += part[((long)dc * 2 + 1) * 6144 + col];
  }
  float b = b_ada[col];
  mods[col] = a0 + b;
  mods[6144 + col] = a1 + b;
}

// ---------------- LayerNorm + modulate -> bf16 ----------------
__global__ void k_ln_mod(const float* __restrict__ x, const float* __restrict__ mods,
                         short* __restrict__ out, int sh_off, int sc_off) {
  int row = blockIdx.x, tid = threadIdx.x, b = row >> 11;
  float4 v = ((const float4*)(x + (long)row * 1024))[tid];
  float s = v.x + v.y + v.z + v.w;
  float ss = v.x * v.x + v.y * v.y + v.z * v.z + v.w * v.w;
  #pragma unroll
  for (int off = 1; off < 64; off <<= 1) { s += __shfl_xor(s, off); ss += __shfl_xor(ss, off); }
  __shared__ float rs[4], rq[4];
  if ((tid & 63) == 0) { rs[tid >> 6] = s; rq[tid >> 6] = ss; }
  __syncthreads();
  s = rs[0] + rs[1] + rs[2] + rs[3];
  ss = rq[0] + rq[1] + rq[2] + rq[3];
  float mu = s * (1.f / 1024.f);
  float rstd = rsqrtf(ss * (1.f / 1024.f) - mu * mu + 1e-6f);
  const float* shv = mods + b * 6144 + sh_off;
  const float* scv = mods + b * 6144 + sc_off;
  int c0 = tid * 4;
  float xs[4] = {v.x, v.y, v.z, v.w};
  s16x4 ov;
  #pragma unroll
  for (int j = 0; j < 4; j++)
    ov[j] = f2bf((xs[j] - mu) * rstd * (1.f + scv[c0 + j]) + shv[c0 + j]);
  ((s16x4*)(out + (long)row * 1024))[tid] = ov;
}

// ---------------- beta = sigmoid(xm @ WbT^T) via MFMA -> [4096][16] fp32 ----------------
__global__ __launch_bounds__(256) void k_beta_mfma(
    const short* __restrict__ xm, const short* __restrict__ WbT,
    float* __restrict__ beta) {
  int tid = threadIdx.x, w = tid >> 6, l = tid & 63;
  int lr = l & 15, lg = l >> 4;
  int row0 = blockIdx.x * 64 + w * 16;
  const short* ap = xm + (long)(row0 + lr) * 1024 + lg * 8;
  const short* bp = WbT + lr * 1024 + lg * 8;
  f32x4 acc = (f32x4){0.f, 0.f, 0.f, 0.f};
  #pragma unroll 8
  for (int kk = 0; kk < 1024; kk += 32) {
    bf16x8 a = *(const bf16x8*)(ap + kk);
    bf16x8 b = *(const bf16x8*)(bp + kk);
    acc = mfma16(a, b, acc);
  }
  #pragma unroll
  for (int i = 0; i < 4; i++) {
    int row = row0 + lg * 4 + i;
    beta[row * 16 + lr] = 1.f / (1.f + expf(-acc[i]));
  }
}

// ---- time-tiled causal conv(4)+SiLU, 4 rows/block, register history ----
// grid 1024 x 384 thr. Each thread owns 8 cols; history x[t-3..t-1] carried
// in regs across the 4 rows -> each qkv row read ~once (vs 4x before).
__global__ __launch_bounds__(384) void k_conv3t(
    const short* __restrict__ qkv, const float* __restrict__ wcq,
    const float* __restrict__ wck, const float* __restrict__ wcv,
    short* __restrict__ qbf, short* __restrict__ kb, short* __restrict__ vb) {
  int r0 = blockIdx.x * 4;
  int tid = threadIdx.x;
  int c0 = tid * 8;
  int seg = c0 >> 10;
  int lc = c0 & 1023;
  const float* wseg = (seg == 0) ? wcq : (seg == 1) ? wck : wcv;
  short* outp = (seg == 0) ? qbf : (seg == 1) ? kb : vb;
  float wt[4][8];
  #pragma unroll
  for (int j = 0; j < 8; j++) {
    float4 wv = *(const float4*)(wseg + (long)(lc + j) * 4);
    wt[0][j] = wv.x; wt[1][j] = wv.y; wt[2][j] = wv.z; wt[3][j] = wv.w;
  }
  float h0[8], h1[8], h2[8];
  int t0 = r0 & 2047;
  if (t0 == 0) {
    #pragma unroll
    for (int j = 0; j < 8; j++) { h0[j] = 0.f; h1[j] = 0.f; h2[j] = 0.f; }
  } else {
    bf16x8 a = *(const bf16x8*)(qkv + (long)(r0 - 3) * 3072 + c0);
    bf16x8 b = *(const bf16x8*)(qkv + (long)(r0 - 2) * 3072 + c0);
    bf16x8 d = *(const bf16x8*)(qkv + (long)(r0 - 1) * 3072 + c0);
    #pragma unroll
    for (int j = 0; j < 8; j++) { h0[j] = bf2f(a[j]); h1[j] = bf2f(b[j]); h2[j] = bf2f(d[j]); }
  }
  #pragma unroll
  for (int rr = 0; rr < 4; rr++) {
    int r = r0 + rr;
    bf16x8 xv = *(const bf16x8*)(qkv + (long)r * 3072 + c0);
    float xc[8], y[8];
    #pragma unroll
    for (int j = 0; j < 8; j++) {
      xc[j] = bf2f(xv[j]);
      float a = h0[j] * wt[0][j] + h1[j] * wt[1][j] + h2[j] * wt[2][j] + xc[j] * wt[3][j];
      y[j] = a / (1.f + __expf(-a));  // SiLU
    }
    if (seg < 2) {  // l2norm over head = 64 cols = 8 adjacent lanes
      float ssq = 0.f;
      #pragma unroll
      for (int j = 0; j < 8; j++) ssq += y[j] * y[j];
      #pragma unroll
      for (int off = 1; off < 8; off <<= 1) ssq += __shfl_xor(ssq, off);
      float sc = rsqrtf(ssq + 1e-6f) * ((seg == 0) ? 0.125f : 1.f);
      #pragma unroll
      for (int j = 0; j < 8; j++) y[j] *= sc;
    }
    bf16x8 ov;
    #pragma unroll
    for (int j = 0; j < 8; j++) ov[j] = f2bf(y[j]);
    *(bf16x8*)(outp + (long)r * 1024 + lc) = ov;
    #pragma unroll
    for (int j = 0; j < 8; j++) { h0[j] = h1[j]; h1[j] = h2[j]; h2[j] = xc[j]; }
  }
}

// ---------------- phase A (MFMA + blocked inverse), bf16 k/v inputs ----------------
__global__ __launch_bounds__(256) void k_phaseA(
    const short* __restrict__ kb, const short* __restrict__ vb,
    const short* __restrict__ qbf, const float* __restrict__ beta,
    short* __restrict__ Wc, short* __restrict__ UTc,
    short* __restrict__ Lc, short* __restrict__ KTc) {
  int chunk = blockIdx.x, chain = blockIdx.y;
  int b = chain >> 4, h = chain & 15;
  long rowbase = (long)b * 2048 + chunk * 64;
  int col0 = h * 64;
  long cb = ((long)chain * 32 + chunk) * 4096;
  __shared__ short Kb[64][72], KTb[64][72], VTb[64][72], Mb[64][72];
  __shared__ float Sf[64][65], Mf[64][65];
  __shared__ float Tl[4][16][20];
  __shared__ float bl[64];
  int tid = threadIdx.x, w = tid >> 6, l = tid & 63;
  int lr = l & 15, lg = l >> 4;

  for (int i = tid; i < 64 * 65; i += 256) (&Mf[0][0])[i] = 0.f;
  {
    int t = tid & 63, g = tid >> 6;
    if (tid < 64) bl[tid] = beta[(rowbase + tid) * 16 + h];
    int dk0 = g * 16;
    bf16x8 kv0 = *(const bf16x8*)(kb + (rowbase + t) * 1024 + col0 + dk0);
    bf16x8 kv1 = *(const bf16x8*)(kb + (rowbase + t) * 1024 + col0 + dk0 + 8);
    bf16x8 vv0 = *(const bf16x8*)(vb + (rowbase + t) * 1024 + col0 + dk0);
    bf16x8 vv1 = *(const bf16x8*)(vb + (rowbase + t) * 1024 + col0 + dk0 + 8);
    *(bf16x8*)&Kb[t][dk0] = kv0;
    *(bf16x8*)&Kb[t][dk0 + 8] = kv1;
    #pragma unroll
    for (int j = 0; j < 8; j++) {
      KTb[dk0 + j][t] = kv0[j];
      KTb[dk0 + 8 + j][t] = kv1[j];
      VTb[dk0 + j][t] = vv0[j];
      VTb[dk0 + 8 + j][t] = vv1[j];
    }
  }
  __syncthreads();
  {
    bf16x8 af0 = *(const bf16x8*)&Kb[w * 16 + lr][lg * 8];
    bf16x8 af1 = *(const bf16x8*)&Kb[w * 16 + lr][32 + lg * 8];
    #pragma unroll
    for (int nt = 0; nt < 4; nt++) {
      f32x4 acc = (f32x4){0.f, 0.f, 0.f, 0.f};
      acc = mfma16(af0, *(const bf16x8*)&Kb[nt * 16 + lr][lg * 8], acc);
      acc = mfma16(af1, *(const bf16x8*)&Kb[nt * 16 + lr][32 + lg * 8], acc);
      #pragma unroll
      for (int i = 0; i < 4; i++) {
        int row = w * 16 + lg * 4 + i, col = nt * 16 + lr;
        Sf[row][col] = (col < row) ? bl[row] * acc[i] : 0.f;
      }
    }
  }
  __syncthreads();
  if (w == 0) {
    int blk = l >> 4, colc = l & 15, base = blk * 16;
    float mcol[16];
    #pragma unroll
    for (int r = 0; r < 16; r++) {
      float s = (r == colc) ? 1.f : 0.f;
      #pragma unroll
      for (int j = 0; j < 16; j++)
        if (j < r) s -= Sf[base + r][base + j] * mcol[j];
      mcol[r] = s;
    }
    #pragma unroll
    for (int r = 0; r < 16; r++) Mf[base + r][base + colc] = mcol[r];
  } else if (w <= 2) {
    int idx = (w - 1) * 64 + l;
    #pragma unroll
    for (int i = 0; i < 4; i++) {
      int v = idx * 4 + i, row = v >> 3, cg = (v & 7) * 8;
      *(bf16x8*)&KTc[cb + row * 64 + cg] = *(const bf16x8*)&KTb[row][cg];
    }
  }
  __syncthreads();
  if (w < 3) {
    int j = w;
    int r = l & 15, c4 = (l >> 4) * 4;
    for (int i = j + 1; i < 4; i++) {
      float t4[4] = {0.f, 0.f, 0.f, 0.f};
      for (int k = j; k < i; k++) {
        #pragma unroll
        for (int m = 0; m < 16; m++) {
          float a = Sf[i * 16 + r][k * 16 + m];
          #pragma unroll
          for (int ii = 0; ii < 4; ii++)
            t4[ii] += a * Mf[k * 16 + m][j * 16 + c4 + ii];
        }
      }
      #pragma unroll
      for (int ii = 0; ii < 4; ii++) Tl[w][r][c4 + ii] = t4[ii];
      float o4[4] = {0.f, 0.f, 0.f, 0.f};
      #pragma unroll
      for (int m = 0; m < 16; m++) {
        float d = Mf[i * 16 + r][i * 16 + m];
        #pragma unroll
        for (int ii = 0; ii < 4; ii++) o4[ii] += d * Tl[w][m][c4 + ii];
      }
      #pragma unroll
      for (int ii = 0; ii < 4; ii++) Mf[i * 16 + r][j * 16 + c4 + ii] = -o4[ii];
    }
  }
  __syncthreads();
  {
    int r = tid >> 2, c0 = (tid & 3) * 16;
    #pragma unroll
    for (int j2 = 0; j2 < 16; j2++)
      Mb[r][c0 + j2] = f2bf(Mf[r][c0 + j2] * bl[c0 + j2]);
  }
  __syncthreads();
  {
    bf16x8 am0 = *(const bf16x8*)&Mb[w * 16 + lr][lg * 8];
    bf16x8 am1 = *(const bf16x8*)&Mb[w * 16 + lr][32 + lg * 8];
    bf16x8 av0 = *(const bf16x8*)&VTb[w * 16 + lr][lg * 8];
    bf16x8 av1 = *(const bf16x8*)&VTb[w * 16 + lr][32 + lg * 8];
    long qoff = (rowbase + w * 16 + lr) * 1024 + col0 + lg * 8;
    bf16x8 aq0 = *(const bf16x8*)&qbf[qoff];
    bf16x8 aq1 = *(const bf16x8*)&qbf[qoff + 32];
    #pragma unroll
    for (int nt = 0; nt < 4; nt++) {
      f32x4 wa = (f32x4){0.f, 0.f, 0.f, 0.f};
      f32x4 ua = (f32x4){0.f, 0.f, 0.f, 0.f};
      f32x4 la = (f32x4){0.f, 0.f, 0.f, 0.f};
      wa = mfma16(am0, *(const bf16x8*)&KTb[nt * 16 + lr][lg * 8], wa);
      wa = mfma16(am1, *(const bf16x8*)&KTb[nt * 16 + lr][32 + lg * 8], wa);
      ua = mfma16(av0, *(const bf16x8*)&Mb[nt * 16 + lr][lg * 8], ua);
      ua = mfma16(av1, *(const bf16x8*)&Mb[nt * 16 + lr][32 + lg * 8], ua);
      la = mfma16(aq0, *(const bf16x8*)&Kb[nt * 16 + lr][lg * 8], la);
      la = mfma16(aq1, *(const bf16x8*)&Kb[nt * 16 + lr][32 + lg * 8], la);
      #pragma unroll
      for (int i = 0; i < 4; i++) {
        int row = w * 16 + lg * 4 + i, col = nt * 16 + lr;
        Wc[cb + row * 64 + col] = f2bf(wa[i]);
        UTc[cb + row * 64 + col] = f2bf(ua[i]);
        Lc[cb + row * 64 + col] = f2bf((col <= row) ? la[i] : 0.f);
      }
    }
  }
}

// ---------------- phase B sequential: state scan only, dv-sliced ----------------
__global__ __launch_bounds__(256) void k_phaseB_seq(
    const short* __restrict__ Wc, const short* __restrict__ UTc,
    const short* __restrict__ KTc, short* __restrict__ STb, short* __restrict__ DTb) {
  int ds = blockIdx.x, chain = blockIdx.y;
  __shared__ short Wl[2][64][72];
  __shared__ short Kl[2][64][72];
  __shared__ short Ul[2][16][72];
  __shared__ float STf[16][68];
  __shared__ short Sb[16][72];
  __shared__ short DTl[16][72];
  int tid = threadIdx.x, w = tid >> 6, l = tid & 63;
  int lr = l & 15, lg = l >> 4;
  for (int i = tid; i < 16 * 68; i += 256) (&STf[0][0])[i] = 0.f;
  for (int i = tid; i < 16 * 72; i += 256) (&Sb[0][0])[i] = 0;
  int srow = tid >> 2, scol = (tid & 3) * 16;
  int ur = tid >> 4, uc = (tid & 15) * 4;
  bf16x8 wreg0, wreg1, kreg0, kreg1;
  s16x4 ureg;
  {
    long cb = (long)chain * 32 * 4096;
    wreg0 = *(const bf16x8*)&Wc[cb + srow * 64 + scol];
    wreg1 = *(const bf16x8*)&Wc[cb + srow * 64 + scol + 8];
    kreg0 = *(const bf16x8*)&KTc[cb + srow * 64 + scol];
    kreg1 = *(const bf16x8*)&KTc[cb + srow * 64 + scol + 8];
    ureg  = *(const s16x4*)&UTc[cb + (ds * 16 + ur) * 64 + uc];
  }
  *(bf16x8*)&Wl[0][srow][scol] = wreg0;
  *(bf16x8*)&Wl[0][srow][scol + 8] = wreg1;
  *(bf16x8*)&Kl[0][srow][scol] = kreg0;
  *(bf16x8*)&Kl[0][srow][scol + 8] = kreg1;
  *(s16x4*)&Ul[0][ur][uc] = ureg;
  __syncthreads();
  int cur = 0;
  for (int c = 0; c < 32; c++) {
    if (c + 1 < 32) {
      long cb = ((long)chain * 32 + c + 1) * 4096;
      wreg0 = *(const bf16x8*)&Wc[cb + srow * 64 + scol];
      wreg1 = *(const bf16x8*)&Wc[cb + srow * 64 + scol + 8];
      kreg0 = *(const bf16x8*)&KTc[cb + srow * 64 + scol];
      kreg1 = *(const bf16x8*)&KTc[cb + srow * 64 + scol + 8];
      ureg  = *(const s16x4*)&UTc[cb + (ds * 16 + ur) * 64 + uc];
    }
    {
      long so = (((long)chain * 32 + c) * 64 + ds * 16 + ur) * 64 + uc;
      *(s16x4*)&STb[so] = *(const s16x4*)&Sb[ur][uc];
    }
    bf16x8 afr0 = *(const bf16x8*)&Sb[lr][lg * 8];
    bf16x8 afr1 = *(const bf16x8*)&Sb[lr][32 + lg * 8];
    f32x4 dacc = (f32x4){0.f, 0.f, 0.f, 0.f};
    dacc = mfma16(afr0, *(const bf16x8*)&Wl[cur][w * 16 + lr][lg * 8], dacc);
    dacc = mfma16(afr1, *(const bf16x8*)&Wl[cur][w * 16 + lr][32 + lg * 8], dacc);
    #pragma unroll
    for (int i = 0; i < 4; i++) {
      int dv = lg * 4 + i, tt = w * 16 + lr;
      float u = bf2f(Ul[cur][dv][tt]);
      short d = f2bf(u - dacc[i]);
      DTl[dv][tt] = d;
      DTb[(((long)chain * 32 + c) * 64 + ds * 16 + dv) * 64 + tt] = d;
    }
    __syncthreads();
    bf16x8 ad0 = *(const bf16x8*)&DTl[lr][lg * 8];
    bf16x8 ad1 = *(const bf16x8*)&DTl[lr][32 + lg * 8];
    f32x4 sacc;
    #pragma unroll
    for (int i = 0; i < 4; i++) sacc[i] = STf[lg * 4 + i][w * 16 + lr];
    sacc = mfma16(ad0, *(const bf16x8*)&Kl[cur][w * 16 + lr][lg * 8], sacc);
    sacc = mfma16(ad1, *(const bf16x8*)&Kl[cur][w * 16 + lr][32 + lg * 8], sacc);
    #pragma unroll
    for (int i = 0; i < 4; i++) {
      STf[lg * 4 + i][w * 16 + lr] = sacc[i];
      Sb[lg * 4 + i][w * 16 + lr] = f2bf(sacc[i]);
    }
    __syncthreads();
    if (c + 1 < 32) {
      int nxt = cur ^ 1;
      *(bf16x8*)&Wl[nxt][srow][scol] = wreg0;
      *(bf16x8*)&Wl[nxt][srow][scol + 8] = wreg1;
      *(bf16x8*)&Kl[nxt][srow][scol] = kreg0;
      *(bf16x8*)&Kl[nxt][srow][scol + 8] = kreg1;
      *(s16x4*)&Ul[nxt][ur][uc] = ureg;
      cur = nxt;
      __syncthreads();
    }
  }
}

// ---------------- phase B parallel: O = Q S_c + L D_c, fused per-head RMSNorm ----------------
__global__ __launch_bounds__(256) void k_phaseBo(
    const short* __restrict__ STb, const short* __restrict__ DTb,
    const short* __restrict__ Lc, const short* __restrict__ qbf,
    const float* __restrict__ wn, short* __restrict__ on) {
  int chunk = blockIdx.x, chain = blockIdx.y;
  int b = chain >> 4, h = chain & 15;
  int tid = threadIdx.x, w = tid >> 6, l = tid & 63;
  int lr = l & 15, lg = l >> 4;
  long cb = ((long)chain * 32 + chunk) * 4096;
  long rowbase = (long)b * 2048 + chunk * 64;
  bf16x8 aq[2], alf[2];
  long qoff = (rowbase + w * 16 + lr) * 1024 + h * 64 + lg * 8;
  aq[0] = *(const bf16x8*)&qbf[qoff];
  aq[1] = *(const bf16x8*)&qbf[qoff + 32];
  alf[0] = *(const bf16x8*)&Lc[cb + (w * 16 + lr) * 64 + lg * 8];
  alf[1] = *(const bf16x8*)&Lc[cb + (w * 16 + lr) * 64 + 32 + lg * 8];
  f32x4 oacc[4];
  #pragma unroll
  for (int nt = 0; nt < 4; nt++) {
    oacc[nt] = (f32x4){0.f, 0.f, 0.f, 0.f};
    #pragma unroll
    for (int kk = 0; kk < 2; kk++) {
      bf16x8 bs = *(const bf16x8*)&STb[cb + (nt * 16 + lr) * 64 + kk * 32 + lg * 8];
      oacc[nt] = mfma16(aq[kk], bs, oacc[nt]);
      bf16x8 bd = *(const bf16x8*)&DTb[cb + (nt * 16 + lr) * 64 + kk * 32 + lg * 8];
      oacc[nt] = mfma16(alf[kk], bd, oacc[nt]);
    }
  }
  float ss[4];
  #pragma unroll
  for (int i = 0; i < 4; i++) {
    ss[i] = 0.f;
    #pragma unroll
    for (int nt = 0; nt < 4; nt++) ss[i] += oacc[nt][i] * oacc[nt][i];
  }
  #pragma unroll
  for (int off = 1; off < 16; off <<= 1) {
    #pragma unroll
    for (int i = 0; i < 4; i++) ss[i] += __shfl_xor(ss[i], off);
  }
  float rr[4];
  #pragma unroll
  for (int i = 0; i < 4; i++) rr[i] = rsqrtf(ss[i] * (1.f / 64.f) + 1e-6f);
  float wnv[4];
  #pragma unroll
  for (int nt = 0; nt < 4; nt++) wnv[nt] = wn[nt * 16 + lr];
  #pragma unroll
  for (int nt = 0; nt < 4; nt++) {
    #pragma unroll
    for (int i = 0; i < 4; i++) {
      long orow = rowbase + w * 16 + lg * 4 + i;
      on[orow * 1024 + h * 64 + nt * 16 + lr] = f2bf(oacc[nt][i] * rr[i] * wnv[nt]);
    }
  }
}

// ---- shared GEMM epilogue ----
template <int EPI>
__device__ __forceinline__ void gemm_epi(float v, int row, int col, int N, void* C,
                                         const float* P1, const float* P2, const float* P3) {
  if (EPI == 0) {
    ((float*)C)[(long)row * N + col] = v;
  } else if (EPI == 1) {
    int bb = row >> 11;
    ((float*)C)[(long)row * N + col] = P1[(long)row * N + col] + P2[bb * 6144 + 2048 + col] * v;
  } else if (EPI == 2) {
    float t = v + P1[col];
    float y = 1.5957691216f * (t + 0.044715f * t * t * t);
    float g = t / (1.f + __expf(-y));
    ((short*)C)[(long)row * N + col] = f2bf(g);
  } else if (EPI == 3) {
    int bb = row >> 11;
    ((float*)C)[(long)row * N + col] =
        P1[(long)row * 1024 + col] + P2[bb * 6144 + 5120 + col] * (v + P3[col]);
  } else {
    ((short*)C)[(long)row * N + col] = f2bf(v);
  }
}

// --- 128x128 single-buffer m97-shape GEMM: 256 thr, 4 waves (2x2, 64x64/wave),
// acc[4][4], 32KB LDS, T2 swizzle, T1 block swizzle. For W1 and QKV (>=3 blocks/CU).
template <int EPI>
__global__ __launch_bounds__(256) void k_gemm128m(
    const short* __restrict__ A, const short* __restrict__ BT, void* __restrict__ C,
    int M, int N, int K,
    const float* __restrict__ P1, const float* __restrict__ P2, const float* __restrict__ P3) {
  __shared__ short As[128 * 64];
  __shared__ short Bs[128 * 64];
  int tid = threadIdx.x, w = tid >> 6, l = tid & 63;
  int lr = l & 15, lg = l >> 4;
  int wr = w >> 1, wc = w & 1;
  int nx = gridDim.x;
  int orig = blockIdx.y * nx + blockIdx.x;
  int cpx = (nx * gridDim.y) >> 3;
  int swz = (orig & 7) * cpx + (orig >> 3);
  int bx = swz % nx, by = swz / nx;
  int row0 = by * 128, col0 = bx * 128;
  int scol = ((l & 7) ^ (l >> 3)) * 8;
  const short* Ab = A + (long)(row0 + w * 8 + (l >> 3)) * K + scol;
  const short* Bb = BT + (long)(col0 + w * 8 + (l >> 3)) * K + scol;
  f32x4 acc[4][4];
  #pragma unroll
  for (int m = 0; m < 4; m++)
    #pragma unroll
    for (int n = 0; n < 4; n++) acc[m][n] = (f32x4){0.f, 0.f, 0.f, 0.f};
  int u0 = ((0 + lg) ^ (lr & 7)) * 8;
  int u1 = ((4 + lg) ^ (lr & 7)) * 8;

  for (int kt = 0; kt < K; kt += 64) {
    #pragma unroll
    for (int i = 0; i < 4; i++) {
      gload16(Ab + (long)i * 32 * K + kt, &As[(i * 32 + w * 8) * 64]);
      gload16(Bb + (long)i * 32 * K + kt, &Bs[(i * 32 + w * 8) * 64]);
    }
    __syncthreads();
    {
      bf16x8 af[4], bv[4];
      #pragma unroll
      for (int m = 0; m < 4; m++)
        af[m] = *(const bf16x8*)&As[(wr * 64 + m * 16 + lr) * 64 + u0];
      #pragma unroll
      for (int n = 0; n < 4; n++)
        bv[n] = *(const bf16x8*)&Bs[(wc * 64 + n * 16 + lr) * 64 + u0];
      #pragma unroll
      for (int m = 0; m < 4; m++)
        #pragma unroll
        for (int n = 0; n < 4; n++)
          acc[m][n] = mfma16(af[m], bv[n], acc[m][n]);
      #pragma unroll
      for (int m = 0; m < 4; m++)
        af[m] = *(const bf16x8*)&As[(wr * 64 + m * 16 + lr) * 64 + u1];
      #pragma unroll
      for (int n = 0; n < 4; n++)
        bv[n] = *(const bf16x8*)&Bs[(wc * 64 + n * 16 + lr) * 64 + u1];
      #pragma unroll
      for (int m = 0; m < 4; m++)
        #pragma unroll
        for (int n = 0; n < 4; n++)
          acc[m][n] = mfma16(af[m], bv[n], acc[m][n]);
    }
    __syncthreads();
  }

  #pragma unroll
  for (int m = 0; m < 4; m++)
    #pragma unroll
    for (int n = 0; n < 4; n++) {
      int col = col0 + wc * 64 + n * 16 + lr;
      #pragma unroll
      for (int i = 0; i < 4; i++)
        gemm_epi<EPI>(acc[m][n][i], row0 + wr * 64 + m * 16 + lg * 4 + i, col, N, C, P1, P2, P3);
    }
}

// --- 64x128-tile dbuf bf16 MFMA GEMM, 8 waves (2Mx4N, 32x32/wave), T2+T1 ---
// 48KB LDS -> 2 blocks/CU; for grid-capped N=1024 GEMMs (Wo/W2: 512 blocks).
template <int EPI>
__global__ __launch_bounds__(512, 4) void k_gemm64(
    const short* __restrict__ A, const short* __restrict__ BT, void* __restrict__ C,
    int M, int N, int K,
    const float* __restrict__ P1, const float* __restrict__ P2, const float* __restrict__ P3) {
  __shared__ short As[2][64 * 64];
  __shared__ short Bs[2][128 * 64];
  int tid = threadIdx.x, w = tid >> 6, l = tid & 63;
  int lr = l & 15, lg = l >> 4;
  int wr = w >> 2, wc = w & 3;
  int nx = gridDim.x;
  int orig = blockIdx.y * nx + blockIdx.x;
  int cpx = (nx * gridDim.y) >> 3;
  int swz = (orig & 7) * cpx + (orig >> 3);
  int bx = swz % nx, by = swz / nx;
  int row0 = by * 64, col0 = bx * 128;
  int scol = ((l & 7) ^ (l >> 3)) * 8;
  const short* Ab = A + (long)(row0 + w * 8 + (l >> 3)) * K + scol;
  const short* Bb = BT + (long)(col0 + w * 8 + (l >> 3)) * K + scol;
  f32x4 acc[2][2];
  #pragma unroll
  for (int m = 0; m < 2; m++)
    #pragma unroll
    for (int n = 0; n < 2; n++) acc[m][n] = (f32x4){0.f, 0.f, 0.f, 0.f};
  int u0 = ((0 + lg) ^ (lr & 7)) * 8;
  int u1 = ((4 + lg) ^ (lr & 7)) * 8;

#define STAGE_S(buf, kt)                                                        \
  {                                                                             \
    gload16(Ab + (kt), &As[buf][(w * 8) * 64]);                                 \
    _Pragma("unroll") for (int i = 0; i < 2; i++)                               \
      gload16(Bb + (long)i * 64 * K + (kt), &Bs[buf][(i * 64 + w * 8) * 64]);   \
  }
#define COMPUTE_S(buf)                                                          \
  {                                                                             \
    bf16x8 af[2], bv[2];                                                        \
    _Pragma("unroll") for (int m = 0; m < 2; m++)                               \
      af[m] = *(const bf16x8*)&As[buf][(wr * 32 + m * 16 + lr) * 64 + u0];      \
    _Pragma("unroll") for (int n = 0; n < 2; n++)                               \
      bv[n] = *(const bf16x8*)&Bs[buf][(wc * 32 + n * 16 + lr) * 64 + u0];      \
    _Pragma("unroll") for (int m = 0; m < 2; m++)                               \
      _Pragma("unroll") for (int n = 0; n < 2; n++)                             \
        acc[m][n] = mfma16(af[m], bv[n], acc[m][n]);                            \
    _Pragma("unroll") for (int m = 0; m < 2; m++)                               \
      af[m] = *(const bf16x8*)&As[buf][(wr * 32 + m * 16 + lr) * 64 + u1];      \
    _Pragma("unroll") for (int n = 0; n < 2; n++)                               \
      bv[n] = *(const bf16x8*)&Bs[buf][(wc * 32 + n * 16 + lr) * 64 + u1];      \
    _Pragma("unroll") for (int m = 0; m < 2; m++)                               \
      _Pragma("unroll") for (int n = 0; n < 2; n++)                             \
        acc[m][n] = mfma16(af[m], bv[n], acc[m][n]);                            \
  }

  STAGE_S(0, 0);
  __syncthreads();
  int cur = 0;
  int ktLast = K - 64;
  for (int kt = 0; kt < ktLast; kt += 64) {
    STAGE_S(cur ^ 1, kt + 64);
    COMPUTE_S(cur);
    __syncthreads();
    cur ^= 1;
  }
  COMPUTE_S(cur);
#undef STAGE_S
#undef COMPUTE_S

  #pragma unroll
  for (int m = 0; m < 2; m++)
    #pragma unroll
    for (int n = 0; n < 2; n++) {
      int col = col0 + wc * 32 + n * 16 + lr;
      #pragma unroll
      for (int i = 0; i < 4; i++)
        gemm_epi<EPI>(acc[m][n][i], row0 + wr * 32 + m * 16 + lg * 4 + i, col, N, C, P1, P2, P3);
    }
}

// ---------------- workspace layout (bytes) ----------------
#define OFF_MODS  0L
#define OFF_MODSP 49152L
#define OFF_XM    442368L
#define OFF_QKV   8830976L
#define OFF_QBF   59162624L
#define OFF_KF    67551232L
#define OFF_VF    84328448L
#define OFF_BETA  101105664L
#define OFF_WC    101367808L
#define OFF_UT    109756416L
#define OFF_LC    118145024L
#define OFF_KT    126533632L
#define OFF_ON    134922240L
#define OFF_X2    143310848L
#define OFF_WQT   160088064L
#define OFF_WKT   162185216L
#define OFF_WVT   164282368L
#define OFF_WOT   166379520L
#define OFF_W1T   168476672L
#define OFF_W2T   176865280L
#define OFF_WBT   185253888L
#define OFF_STB   OFF_QKV
#define OFF_DTB   (OFF_QKV + 8388608L)
#define OFF_M1    (OFF_QKV + 16777216L)
#define OFF_H     OFF_XM

extern "C" void kernel_launch(void* const* d_in, const int* in_sizes, int n_in,
                              void* d_out, int out_size, void* d_ws, size_t ws_size,
                              hipStream_t stream) {
  const float* x     = (const float*)d_in[0];
  const float* c     = (const float*)d_in[1];
  const float* W_ada = (const float*)d_in[2];
  const float* b_ada = (const float*)d_in[3];
  const float* Wq    = (const float*)d_in[4];
  const float* Wk    = (const float*)d_in[5];
  const float* Wv    = (const float*)d_in[6];
  const float* Wb    = (const float*)d_in[7];
  const float* wcq   = (const float*)d_in[8];
  const float* wck   = (const float*)d_in[9];
  const float* wcv   = (const float*)d_in[10];
  const float* wn    = (const float*)d_in[11];
  const float* Wo    = (const float*)d_in[12];
  const float* W1    = (const float*)d_in[13];
  const float* b1    = (const float*)d_in[14];
  const float* W2    = (const float*)d_in[15];
  const float* b2    = (const float*)d_in[16];
  float* out = (float*)d_out;
  char* ws = (char*)d_ws;

  float* mods = (float*)(ws + OFF_MODS);
  float* modp = (float*)(ws + OFF_MODSP);
  short* xm   = (short*)(ws + OFF_XM);
  short* qkv  = (short*)(ws + OFF_QKV);
  short* qbf  = (short*)(ws + OFF_QBF);
  short* kb   = (short*)(ws + OFF_KF);
  short* vb   = (short*)(ws + OFF_VF);
  float* beta = (float*)(ws + OFF_BETA);
  short* Wc   = (short*)(ws + OFF_WC);
  short* UTc  = (short*)(ws + OFF_UT);
  short* Lc   = (short*)(ws + OFF_LC);
  short* KTc  = (short*)(ws + OFF_KT);
  short* STb  = (short*)(ws + OFF_STB);
  short* DTb  = (short*)(ws + OFF_DTB);
  short* on   = (short*)(ws + OFF_ON);
  float* x2   = (float*)(ws + OFF_X2);
  short* hbuf = (short*)(ws + OFF_H);
  short* m1   = (short*)(ws + OFF_M1);
  short* WqT  = (short*)(ws + OFF_WQT);
  short* WkT  = (short*)(ws + OFF_WKT);
  short* WvT  = (short*)(ws + OFF_WVT);
  short* WoT  = (short*)(ws + OFF_WOT);
  short* W1T  = (short*)(ws + OFF_W1T);
  short* W2T  = (short*)(ws + OFF_W2T);
  short* WbT  = (short*)(ws + OFF_WBT);

  k_transpose4<<<dim3(32, 32, 4), 256, 0, stream>>>(Wq, Wk, Wv, Wo, WqT, WkT, WvT, WoT);
  k_transpose_bf16<<<dim3(128, 32), 256, 0, stream>>>(W1, W1T, 1024, 4096);
  k_transpose_bf16<<<dim3(32, 128), 256, 0, stream>>>(W2, W2T, 4096, 1024);
  k_transpose_wb<<<64, 256, 0, stream>>>(Wb, WbT);

  k_mods_p1<<<dim3(24, 8), 256, 0, stream>>>(c, W_ada, modp);
  k_mods_p2<<<24, 256, 0, stream>>>(modp, b_ada, mods);
  k_ln_mod<<<4096, 256, 0, stream>>>(x, mods, xm, 0, 1024);

  k_gemm128m<4><<<dim3(24, 32), 256, 0, stream>>>(xm, WqT, qkv, 4096, 3072, 1024,
                                                  nullptr, nullptr, nullptr);
  k_beta_mfma<<<64, 256, 0, stream>>>(xm, WbT, beta);

  k_conv3t<<<1024, 384, 0, stream>>>(qkv, wcq, wck, wcv, qbf, kb, vb);

  k_phaseA<<<dim3(32, 32), 256, 0, stream>>>(kb, vb, qbf, beta, Wc, UTc, Lc, KTc);
  k_phaseB_seq<<<dim3(4, 32), 256, 0, stream>>>(Wc, UTc, KTc, STb, DTb);
  k_phaseBo<<<dim3(32, 32), 256, 0, stream>>>(STb, DTb, Lc, qbf, wn, on);

  k_gemm64<1><<<dim3(8, 64), 512, 0, stream>>>(on, WoT, x2, 4096, 1024, 1024,
                                               x, mods, nullptr);

  k_ln_mod<<<4096, 256, 0, stream>>>(x2, mods, hbuf, 3072, 4096);
  k_gemm128m<2><<<dim3(32, 32), 256, 0, stream>>>(hbuf, W1T, m1, 4096, 4096, 1024,
                                                  b1, nullptr, nullptr);
  k_gemm64<3><<<dim3(8, 64), 512, 0, stream>>>(m1, W2T, out, 4096, 1024, 4096,
                                               x2, mods, b2);
}